// Round 2
// baseline (3118.043 us; speedup 1.0000x reference)
//
#include <hip/hip_runtime.h>

#define B_     2
#define L_     4096
#define DM     1024
#define DI     2048
#define NH     16
#define HD     128
#define NS     64      // D_STATE
#define T_     256     // CHUNK
#define NC     16      // L_/T_
#define CONVD  2176    // DI + 2*NS
#define DPROJ  4240    // DI + CONVD + NH

// ---------------- generic C[m,n] = sum_k A[m,k]*B[n,k] (both row-major) ----------------
__global__ __launch_bounds__(256) void sgemm_abt(
    const float* __restrict__ A, const float* __restrict__ Bm, float* __restrict__ C,
    int M, int N, int K, int lda, int ldb, int ldc)
{
    const int BM = 128, BN = 128, BK = 16;
    __shared__ __align__(16) float As[BK][BM];
    __shared__ __align__(16) float Bs[BK][BN];
    int tid = threadIdx.x;
    int m0 = blockIdx.y * BM;
    int n0 = blockIdx.x * BN;
    int ty = tid / 16, tx = tid % 16;

    float acc[8][8];
    #pragma unroll
    for (int i = 0; i < 8; i++)
        #pragma unroll
        for (int j = 0; j < 8; j++) acc[i][j] = 0.f;

    for (int k0 = 0; k0 < K; k0 += BK) {
        #pragma unroll
        for (int i = 0; i < 2; i++) {
            int f = tid * 2 + i;          // 512 float4 units
            int row = f >> 2;             // 0..127
            int colv = f & 3;             // 0..3
            float4 av = *(const float4*)(A + (size_t)(m0 + row) * lda + k0 + colv * 4);
            As[colv*4+0][row] = av.x; As[colv*4+1][row] = av.y;
            As[colv*4+2][row] = av.z; As[colv*4+3][row] = av.w;
        }
        #pragma unroll
        for (int i = 0; i < 2; i++) {
            int f = tid * 2 + i;
            int row = f >> 2;
            int colv = f & 3;
            float4 bv = make_float4(0.f, 0.f, 0.f, 0.f);
            if (n0 + row < N)
                bv = *(const float4*)(Bm + (size_t)(n0 + row) * ldb + k0 + colv * 4);
            Bs[colv*4+0][row] = bv.x; Bs[colv*4+1][row] = bv.y;
            Bs[colv*4+2][row] = bv.z; Bs[colv*4+3][row] = bv.w;
        }
        __syncthreads();
        #pragma unroll
        for (int kk = 0; kk < BK; kk++) {
            float4 a0 = *(const float4*)&As[kk][ty*8];
            float4 a1 = *(const float4*)&As[kk][ty*8+4];
            float4 b0 = *(const float4*)&Bs[kk][tx*8];
            float4 b1 = *(const float4*)&Bs[kk][tx*8+4];
            float a[8] = {a0.x,a0.y,a0.z,a0.w,a1.x,a1.y,a1.z,a1.w};
            float b[8] = {b0.x,b0.y,b0.z,b0.w,b1.x,b1.y,b1.z,b1.w};
            #pragma unroll
            for (int i = 0; i < 8; i++)
                #pragma unroll
                for (int j = 0; j < 8; j++)
                    acc[i][j] = fmaf(a[i], b[j], acc[i][j]);
        }
        __syncthreads();
    }
    #pragma unroll
    for (int i = 0; i < 8; i++) {
        int m = m0 + ty*8 + i;
        #pragma unroll
        for (int j = 0; j < 8; j++) {
            int n = n0 + tx*8 + j;
            if (n < N) C[(size_t)m * ldc + n] = acc[i][j];
        }
    }
}

// ---------------- depthwise causal conv (width 4) + bias + silu; one batch (L_ rows) ----------------
__global__ void conv_silu(const float* __restrict__ proj, const float* __restrict__ w,
                          const float* __restrict__ bias, float* __restrict__ xbc)
{
    size_t idx = (size_t)blockIdx.x * 256 + threadIdx.x;
    if (idx >= (size_t)L_ * CONVD) return;
    int c = (int)(idx % CONVD);
    int l = (int)(idx / CONVD);
    float acc = bias[c];
    #pragma unroll
    for (int j = 0; j < 4; j++) {
        int ll = l - 3 + j;
        if (ll >= 0)
            acc = fmaf(proj[(size_t)ll * DPROJ + DI + c], w[c*4+j], acc);
    }
    acc = acc / (1.f + expf(-acc));   // silu
    xbc[(size_t)l * CONVD + c] = acc;
}

// ---------------- dt = softplus(dt_raw + bias); acs = cumsum(dt*A) within chunk ----------------
__global__ __launch_bounds__(256) void dt_scan(
    const float* __restrict__ proj, const float* __restrict__ A_log,
    const float* __restrict__ dt_bias, float* __restrict__ dt_t, float* __restrict__ acs)
{
    int blk = blockIdx.x;            // c*NH + h
    int h = blk % NH;
    int c = blk / NH;
    int t = threadIdx.x;
    size_t row = (size_t)(c * T_ + t);
    float raw = proj[row * DPROJ + DI + CONVD + h] + dt_bias[h];
    float dtv = (raw > 20.f) ? raw : log1pf(expf(raw));
    float Ah = -expf(A_log[h]);
    __shared__ float buf[T_];
    buf[t] = dtv * Ah;
    __syncthreads();
    for (int off = 1; off < T_; off <<= 1) {
        float add = (t >= off) ? buf[t - off] : 0.f;
        __syncthreads();
        buf[t] += add;
        __syncthreads();
    }
    size_t o = (size_t)blk * T_ + t;
    dt_t[o] = dtv;
    acs[o]  = buf[t];
}

// ---------------- per-chunk states[p][n] = sum_t x[t,p]*B[t,n]*exp(acs_last-acs[t])*dt[t] ----------------
__global__ __launch_bounds__(256) void chunk_states(
    const float* __restrict__ xbc, const float* __restrict__ dt_t,
    const float* __restrict__ acs, float* __restrict__ states)
{
    int blk = blockIdx.x;            // c*NH + h
    int h = blk % NH;
    int c = blk / NH;
    int tid = threadIdx.x;
    __shared__ float coef[T_];
    __shared__ __align__(16) float xs[32][HD];
    __shared__ float Bs[32][NS + 1];
    {
        size_t o = (size_t)blk * T_;
        float last = acs[o + T_ - 1];
        coef[tid] = expf(last - acs[o + tid]) * dt_t[o + tid];
    }
    __syncthreads();
    int tx = tid % 16;   // n0 = tx*4
    int ty = tid / 16;   // p0 = ty*8
    float acc[8][4];
    #pragma unroll
    for (int i = 0; i < 8; i++)
        #pragma unroll
        for (int j = 0; j < 4; j++) acc[i][j] = 0.f;
    size_t rowbase = (size_t)(c * T_);
    for (int t0 = 0; t0 < T_; t0 += 32) {
        #pragma unroll
        for (int i = 0; i < 4; i++) {           // xs: 32x128 = 1024 float4
            int f = tid * 4 + i;
            int r = f / 32, cv = f % 32;
            float4 v = *(const float4*)(xbc + (rowbase + t0 + r) * CONVD + h * HD + cv * 4);
            *(float4*)&xs[r][cv * 4] = v;
        }
        #pragma unroll
        for (int i = 0; i < 2; i++) {           // Bs: 32x64 = 512 float4, coef-weighted
            int f = tid * 2 + i;
            int r = f / 16, cv = f % 16;
            float4 v = *(const float4*)(xbc + (rowbase + t0 + r) * CONVD + DI + cv * 4);
            float wc = coef[t0 + r];
            Bs[r][cv*4+0] = v.x * wc; Bs[r][cv*4+1] = v.y * wc;
            Bs[r][cv*4+2] = v.z * wc; Bs[r][cv*4+3] = v.w * wc;
        }
        __syncthreads();
        #pragma unroll
        for (int tt = 0; tt < 32; tt++) {
            float xv[8], bv[4];
            #pragma unroll
            for (int i = 0; i < 8; i++) xv[i] = xs[tt][ty*8+i];
            #pragma unroll
            for (int j = 0; j < 4; j++) bv[j] = Bs[tt][tx*4+j];
            #pragma unroll
            for (int i = 0; i < 8; i++)
                #pragma unroll
                for (int j = 0; j < 4; j++)
                    acc[i][j] = fmaf(xv[i], bv[j], acc[i][j]);
        }
        __syncthreads();
    }
    size_t base = (size_t)blk * HD * NS;
    #pragma unroll
    for (int i = 0; i < 8; i++)
        #pragma unroll
        for (int j = 0; j < 4; j++)
            states[base + (size_t)(ty*8+i) * NS + tx*4+j] = acc[i][j];
}

// ---------------- in-place inter-chunk recurrence: states[c] <- prev[c] ----------------
// prev[0]=0; prev[c] = states_old[c-1] + exp(ct[c-1]) * prev[c-1]
__global__ __launch_bounds__(256) void prev_rec(
    float* __restrict__ states, const float* __restrict__ acs)
{
    int blk = blockIdx.x;          // h*4 + pq
    int pq = blk % 4;
    int h = blk / 4;
    int tid = threadIdx.x;
    int s = tid * 8;
    int p = pq * 32 + s / NS;
    int n0 = s % NS;
    float run[8];
    #pragma unroll
    for (int j = 0; j < 8; j++) run[j] = 0.f;
    for (int c = 0; c < NC; c++) {
        size_t ch = (size_t)(c * NH + h);
        size_t off = ch * HD * NS + (size_t)p * NS + n0;
        float sv[8];
        #pragma unroll
        for (int j = 0; j < 8; j++) sv[j] = states[off + j];
        #pragma unroll
        for (int j = 0; j < 8; j++) states[off + j] = run[j];
        float f = expf(acs[ch * T_ + T_ - 1]);
        #pragma unroll
        for (int j = 0; j < 8; j++) run[j] = sv[j] + f * run[j];
    }
}

// ---------------- Y = (Y_diag + Y_off + D*x) * silu(z), written over proj z-columns ----------------
__global__ __launch_bounds__(256) void y_chunk(
    const float* __restrict__ xbc, const float* __restrict__ dt_t,
    const float* __restrict__ acs, const float* __restrict__ prev,
    const float* __restrict__ D_skip, float* zy /* = proj */)
{
    int blk = blockIdx.x;          // ((c*NH)+h)*4 + qt
    int qt = blk % 4;
    int h = (blk / 4) % NH;
    int c = blk / (4 * NH);
    int tid = threadIdx.x;

    __shared__ __align__(16) float Cs[64][NS];
    __shared__ __align__(16) float Bs[64][NS];
    __shared__ float Ss[64][65];
    __shared__ __align__(16) float xs[64][HD];   // reused as ps[128][64] after kt loop
    __shared__ float acs_s[T_], dts[T_];

    size_t bch = (size_t)(c * NH + h);
    acs_s[tid] = acs[bch * T_ + tid];
    dts[tid]   = dt_t[bch * T_ + tid];
    size_t rowbase = (size_t)(c * T_);

    #pragma unroll
    for (int i = 0; i < 4; i++) {             // Cs: 64x64 = 1024 float4
        int f = tid * 4 + i;
        int r = f / 16, cv = f % 16;
        float4 v = *(const float4*)(xbc + (rowbase + qt*64 + r) * CONVD + DI + NS + cv * 4);
        *(float4*)&Cs[r][cv * 4] = v;
    }
    __syncthreads();

    int tx = tid % 16, ty = tid / 16;
    int p0 = tx * 8, q0 = ty * 4;
    float acc[4][8];
    #pragma unroll
    for (int i = 0; i < 4; i++)
        #pragma unroll
        for (int j = 0; j < 8; j++) acc[i][j] = 0.f;

    for (int kt = 0; kt <= qt; kt++) {
        #pragma unroll
        for (int i = 0; i < 4; i++) {         // Bs k-tile
            int f = tid * 4 + i;
            int r = f / 16, cv = f % 16;
            float4 v = *(const float4*)(xbc + (rowbase + kt*64 + r) * CONVD + DI + cv * 4);
            *(float4*)&Bs[r][cv * 4] = v;
        }
        #pragma unroll
        for (int i = 0; i < 8; i++) {         // xs k-tile: 64x128 = 2048 float4
            int f = tid * 8 + i;
            int r = f / 32, cv = f % 32;
            float4 v = *(const float4*)(xbc + (rowbase + kt*64 + r) * CONVD + h * HD + cv * 4);
            *(float4*)&xs[r][cv * 4] = v;
        }
        __syncthreads();
        float sv[4][4];
        #pragma unroll
        for (int qi = 0; qi < 4; qi++) {
            #pragma unroll
            for (int ki = 0; ki < 4; ki++) sv[qi][ki] = 0.f;
            #pragma unroll
            for (int n = 0; n < NS; n++) {
                float cq = Cs[ty*4+qi][n];
                #pragma unroll
                for (int ki = 0; ki < 4; ki++)
                    sv[qi][ki] = fmaf(cq, Bs[tx*4+ki][n], sv[qi][ki]);
            }
        }
        #pragma unroll
        for (int qi = 0; qi < 4; qi++) {
            int qg = qt*64 + ty*4 + qi;
            #pragma unroll
            for (int ki = 0; ki < 4; ki++) {
                int kg = kt*64 + tx*4 + ki;
                float val = 0.f;
                if (qg >= kg)
                    val = sv[qi][ki] * expf(acs_s[qg] - acs_s[kg]) * dts[kg];
                Ss[ty*4+qi][tx*4+ki] = val;
            }
        }
        __syncthreads();
        #pragma unroll
        for (int kk = 0; kk < 64; kk++) {
            float xv[8];
            #pragma unroll
            for (int j = 0; j < 8; j++) xv[j] = xs[kk][p0+j];
            #pragma unroll
            for (int qi = 0; qi < 4; qi++) {
                float sq = Ss[q0+qi][kk];
                #pragma unroll
                for (int j = 0; j < 8; j++)
                    acc[qi][j] = fmaf(sq, xv[j], acc[qi][j]);
            }
        }
        __syncthreads();
    }

    // Y_off: acc += exp(acs[q]) * sum_n C[q,n] * prev[p,n]   (ps aliases xs storage)
    float* psbuf = &xs[0][0];                 // 128*64 floats
    #pragma unroll
    for (int i = 0; i < 8; i++) {             // ps: 128x64 = 2048 float4
        int f = tid * 8 + i;
        int r = f / 16, cv = f % 16;
        float4 v = *(const float4*)(prev + bch * HD * NS + (size_t)r * NS + cv * 4);
        *(float4*)&psbuf[r * NS + cv * 4] = v;
    }
    __syncthreads();
    #pragma unroll
    for (int qi = 0; qi < 4; qi++) {
        float eq = expf(acs_s[qt*64 + q0 + qi]);
        for (int n = 0; n < NS; n++) {
            float cv = Cs[q0+qi][n] * eq;
            #pragma unroll
            for (int j = 0; j < 8; j++)
                acc[qi][j] = fmaf(cv, psbuf[(p0+j) * NS + n], acc[qi][j]);
        }
    }

    float Dh = D_skip[h];
    #pragma unroll
    for (int qi = 0; qi < 4; qi++) {
        size_t row = rowbase + qt*64 + q0 + qi;
        const float* xr = xbc + row * CONVD + h * HD;
        float* yr = zy + row * DPROJ + h * HD;   // z lives at proj cols [0,DI)
        #pragma unroll
        for (int j = 0; j < 8; j++) {
            float zv = yr[p0+j];
            float g = zv / (1.f + expf(-zv));    // silu(z)
            yr[p0+j] = (acc[qi][j] + Dh * xr[p0+j]) * g;
        }
    }
}

extern "C" void kernel_launch(void* const* d_in, const int* in_sizes, int n_in,
                              void* d_out, int out_size, void* d_ws, size_t ws_size,
                              hipStream_t stream)
{
    const float* x       = (const float*)d_in[0];
    const float* W_in    = (const float*)d_in[1];
    const float* conv_w  = (const float*)d_in[2];
    const float* conv_b  = (const float*)d_in[3];
    const float* A_log   = (const float*)d_in[4];
    const float* dt_bias = (const float*)d_in[5];
    const float* D_skip  = (const float*)d_in[6];
    const float* W_out   = (const float*)d_in[7];
    float* out = (float*)d_out;

    // per-batch workspace (~109 MB total)
    float* proj   = (float*)d_ws;                          // L_*DPROJ
    float* xbc    = proj   + (size_t)L_ * DPROJ;           // L_*CONVD
    float* dt_t   = xbc    + (size_t)L_ * CONVD;           // NC*NH*T_
    float* acs    = dt_t   + (size_t)NC * NH * T_;
    float* states = acs    + (size_t)NC * NH * T_;         // NC*NH*HD*NS

    dim3 blk(256);
    for (int b = 0; b < B_; b++) {
        const float* xb = x + (size_t)b * L_ * DM;
        float* outb = out + (size_t)b * L_ * DM;
        sgemm_abt<<<dim3((DPROJ + 127) / 128, L_ / 128), blk, 0, stream>>>(
            xb, W_in, proj, L_, DPROJ, DM, DM, DM, DPROJ);
        conv_silu<<<dim3((unsigned)(((size_t)L_ * CONVD + 255) / 256)), blk, 0, stream>>>(
            proj, conv_w, conv_b, xbc);
        dt_scan<<<dim3(NC * NH), blk, 0, stream>>>(proj, A_log, dt_bias, dt_t, acs);
        chunk_states<<<dim3(NC * NH), blk, 0, stream>>>(xbc, dt_t, acs, states);
        prev_rec<<<dim3(NH * 4), blk, 0, stream>>>(states, acs);
        y_chunk<<<dim3(NC * NH * 4), blk, 0, stream>>>(xbc, dt_t, acs, states, D_skip, proj);
        sgemm_abt<<<dim3(DM / 128, L_ / 128), blk, 0, stream>>>(
            proj, W_out, outb, L_, DM, DI, DPROJ, DI, DM);
    }
}